// Round 1
// 21497.983 us; speedup vs baseline: 1.4998x; 1.4998x over previous
//
#include <hip/hip_runtime.h>
#include <stdint.h>

#define NBLK 256
#define NTHR 512          // 8 waves: K-split within block
#define BATCH 64
#define HD 1024
#define SEQ 512

// barrier flags: one per 128-B line to avoid MALL slice hotspots
#define FLAG_STRIDE 32

typedef unsigned short u16;
typedef uint32_t u32;
typedef __attribute__((ext_vector_type(8))) short v8s;        // 8 bf16 (MFMA A/B frag)
typedef __attribute__((ext_vector_type(4))) float v4f;        // MFMA C/D frag
typedef __attribute__((ext_vector_type(4))) unsigned int v4u; // dwordx4

__device__ __forceinline__ float bf2f(u16 u){
  union { float f; u32 i; } c; c.i = ((u32)u) << 16; return c.f;
}
__device__ __forceinline__ u16 f2bf(float f){  // round-to-nearest-even
  union { float f; u32 i; } c; c.f = f;
  u32 i = c.i;
  return (u16)((i + 0x7fffu + ((i >> 16) & 1u)) >> 16);
}
__device__ __forceinline__ float sigm(float v){ return 1.f / (1.f + __expf(-v)); }

// packed activation element: low16 = hi bf16, high16 = lo bf16; value = hi + lo
__device__ __forceinline__ u32 packf(float v){
  const u16 hi = f2bf(v);
  const u16 lo = f2bf(v - bf2f(hi));
  return (u32)hi | ((u32)lo << 16);
}
__device__ __forceinline__ float unpackf(u32 w){
  return bf2f((u16)(w & 0xffffu)) + bf2f((u16)(w >> 16));
}

// coherent (cache-bypassing) scalar access
__device__ __forceinline__ u32 ald(const u32* p){
  return __hip_atomic_load(p, __ATOMIC_RELAXED, __HIP_MEMORY_SCOPE_AGENT);
}
__device__ __forceinline__ void ast(u32* p, u32 v){
  __hip_atomic_store(p, v, __ATOMIC_RELAXED, __HIP_MEMORY_SCOPE_AGENT);
}
__device__ __forceinline__ int aldi(const int* p){
  return __hip_atomic_load(p, __ATOMIC_RELAXED, __HIP_MEMORY_SCOPE_AGENT);
}

// ---- batched coherent vector loads: N dwordx4, one waitcnt ----
// offsets: ks*128 + {0,16} bytes (lane's 8 consecutive u32 per 32-element k-step)
__device__ __forceinline__ void ald_batch8(const u32* p, v4u r[8]){
  asm volatile(
    "global_load_dwordx4 %0, %8, off sc0 sc1\n\t"
    "global_load_dwordx4 %1, %8, off offset:16 sc0 sc1\n\t"
    "global_load_dwordx4 %2, %8, off offset:128 sc0 sc1\n\t"
    "global_load_dwordx4 %3, %8, off offset:144 sc0 sc1\n\t"
    "global_load_dwordx4 %4, %8, off offset:256 sc0 sc1\n\t"
    "global_load_dwordx4 %5, %8, off offset:272 sc0 sc1\n\t"
    "global_load_dwordx4 %6, %8, off offset:384 sc0 sc1\n\t"
    "global_load_dwordx4 %7, %8, off offset:400 sc0 sc1\n\t"
    "s_waitcnt vmcnt(0)"
    : "=&v"(r[0]), "=&v"(r[1]), "=&v"(r[2]), "=&v"(r[3]),
      "=&v"(r[4]), "=&v"(r[5]), "=&v"(r[6]), "=&v"(r[7])
    : "v"(p) : "memory");
}
__device__ __forceinline__ void ald_batch16(const u32* p, v4u r[16]){
  asm volatile(
    "global_load_dwordx4 %0, %16, off sc0 sc1\n\t"
    "global_load_dwordx4 %1, %16, off offset:16 sc0 sc1\n\t"
    "global_load_dwordx4 %2, %16, off offset:128 sc0 sc1\n\t"
    "global_load_dwordx4 %3, %16, off offset:144 sc0 sc1\n\t"
    "global_load_dwordx4 %4, %16, off offset:256 sc0 sc1\n\t"
    "global_load_dwordx4 %5, %16, off offset:272 sc0 sc1\n\t"
    "global_load_dwordx4 %6, %16, off offset:384 sc0 sc1\n\t"
    "global_load_dwordx4 %7, %16, off offset:400 sc0 sc1\n\t"
    "global_load_dwordx4 %8, %16, off offset:512 sc0 sc1\n\t"
    "global_load_dwordx4 %9, %16, off offset:528 sc0 sc1\n\t"
    "global_load_dwordx4 %10, %16, off offset:640 sc0 sc1\n\t"
    "global_load_dwordx4 %11, %16, off offset:656 sc0 sc1\n\t"
    "global_load_dwordx4 %12, %16, off offset:768 sc0 sc1\n\t"
    "global_load_dwordx4 %13, %16, off offset:784 sc0 sc1\n\t"
    "global_load_dwordx4 %14, %16, off offset:896 sc0 sc1\n\t"
    "global_load_dwordx4 %15, %16, off offset:912 sc0 sc1\n\t"
    "s_waitcnt vmcnt(0)"
    : "=&v"(r[0]), "=&v"(r[1]), "=&v"(r[2]), "=&v"(r[3]),
      "=&v"(r[4]), "=&v"(r[5]), "=&v"(r[6]), "=&v"(r[7]),
      "=&v"(r[8]), "=&v"(r[9]), "=&v"(r[10]), "=&v"(r[11]),
      "=&v"(r[12]), "=&v"(r[13]), "=&v"(r[14]), "=&v"(r[15])
    : "v"(p) : "memory");
}

struct FragPair { v8s hi; v8s lo; };
// two dwordx4 of packed u32 -> (8 hi bf16, 8 lo bf16)
__device__ __forceinline__ FragPair splitpair(v4u w0, v4u w1){
  union { v8s v; u32 u[4]; } H, L;
#pragma unroll
  for (int i = 0; i < 2; i++){
    H.u[i]     = (w0[2*i] & 0xffffu) | (w0[2*i+1] << 16);
    L.u[i]     = (w0[2*i] >> 16)     | (w0[2*i+1] & 0xffff0000u);
    H.u[2 + i] = (w1[2*i] & 0xffffu) | (w1[2*i+1] << 16);
    L.u[2 + i] = (w1[2*i] >> 16)     | (w1[2*i+1] & 0xffff0000u);
  }
  FragPair f; f.hi = H.v; f.lo = L.v; return f;
}

// ---- full-grid barrier (prep only); flags spread one per 128-B line ----
__device__ __forceinline__ void gbar_all(int* flags, int target, int bid, int tid){
  __syncthreads();
  if (tid == 0)
    __hip_atomic_store(&flags[bid * FLAG_STRIDE], target, __ATOMIC_RELAXED, __HIP_MEMORY_SCOPE_AGENT);
  if (tid < 64){
    const int* p = flags + (tid * 4) * FLAG_STRIDE;
    for (;;){
      int a = aldi(p + 0 * FLAG_STRIDE), b = aldi(p + 1 * FLAG_STRIDE);
      int c = aldi(p + 2 * FLAG_STRIDE), d = aldi(p + 3 * FLAG_STRIDE);
      if (a >= target && b >= target && c >= target && d >= target) break;
      __builtin_amdgcn_s_sleep(1);
    }
  }
  __syncthreads();
}

// ---- 64-block row-group barrier: lane i polls member i's flag (own line each) ----
__device__ __forceinline__ void gbar64(int* gf, int target, int member, int tid){
  __syncthreads();
  if (tid == 0)
    __hip_atomic_store(&gf[member * FLAG_STRIDE], target, __ATOMIC_RELAXED, __HIP_MEMORY_SCOPE_AGENT);
  if (tid < 64){
    while (aldi(&gf[tid * FLAG_STRIDE]) < target) __builtin_amdgcn_s_sleep(1);
  }
  __syncthreads();
}

// ---- pre-barrier weight prefetch (independent of cross-block data) ----
// mog: ALL 4 k-steps prefetched -> zero post-barrier weight loads in mog_phase
struct MogPre { v8s bh[4]; v8s bl[4]; };
__device__ __forceinline__ MogPre mog_pre(const u16* WThi, const u16* WTlo, int cn, int tid){
  const int w = tid >> 6, lane = tid & 63;
  const int mi = lane & 15, q = lane >> 4;
  const int kb = w * 128 + q * 8;
  const u16* bh_p = WThi + (size_t)(cn + mi) * HD + kb;
  const u16* bl_p = WTlo + (size_t)(cn + mi) * HD + kb;
  MogPre pre;
#pragma unroll
  for (int ks = 0; ks < 4; ks++){
    pre.bh[ks] = *(const v8s*)(bh_p + ks * 32);
    pre.bl[ks] = *(const v8s*)(bl_p + ks * 32);
  }
  return pre;
}
// gates: ks=0,1 prefetched pre-barrier (16 v8s = 64 VGPR live across barrier)
struct GatesPre { v8s bh[4][2]; v8s bl[4][2]; };
__device__ __forceinline__ GatesPre gates_pre(
    const u16* WihThi, const u16* WihTlo,
    const u16* WhhThi, const u16* WhhTlo, int cn, int tid){
  const int w = tid >> 6, lane = tid & 63;
  const int mi = lane & 15, q = lane >> 4;
  const int src = w >> 2;
  const u16* Bh = src ? WhhThi : WihThi;
  const u16* Bl = src ? WhhTlo : WihTlo;
  const int kb = (w & 3) * 256 + q * 8;
  GatesPre g;
#pragma unroll
  for (int nt = 0; nt < 4; nt++){
    const size_t brow = (size_t)(nt * HD + cn + mi) * HD + kb;
#pragma unroll
    for (int ks = 0; ks < 2; ks++){
      g.bh[nt][ks] = *(const v8s*)(Bh + brow + ks * 32);
      g.bl[nt][ks] = *(const v8s*)(Bl + brow + ks * 32);
    }
  }
  return g;
}

// ---- one mogrify matmul phase: O = 2*sigmoid(A @ W) * mult ----
__device__ __forceinline__ void mog_phase(
    MogPre pre, const u32* A,
    const float* multx, const u32* M, u32* O,
    int rm, int cn, int tid, float* cb)
{
  const int w = tid >> 6, lane = tid & 63;
  const int mi = lane & 15, q = lane >> 4;
  const int kb = w * 128 + q * 8;
  // epilogue multiplier: issue ASAP (produced >=2 phases ago — always ready)
  const int er = tid >> 4, ec = tid & 15;
  const int gi = (rm + er) * HD + (cn + ec);
  const bool epi = (tid < 256);
  float multv = 0.f; u32 mpack = 0;
  if (epi){
    if (multx) multv = __builtin_nontemporal_load(multx + (size_t)(rm + er) * (SEQ * HD) + (cn + ec));
    else       mpack = ald(M + gi);
  }
  // A: one batched coherent load (single MALL round trip); all B frags already in regs
  v4u ar[8];
  ald_batch8(A + (size_t)(rm + mi) * HD + kb, ar);

  v4f acc = {0.f, 0.f, 0.f, 0.f};
#pragma unroll
  for (int ks = 0; ks < 4; ks++){
    FragPair a = splitpair(ar[2 * ks], ar[2 * ks + 1]);
    acc = __builtin_amdgcn_mfma_f32_16x16x32_bf16(a.hi, pre.bh[ks], acc, 0, 0, 0);
    acc = __builtin_amdgcn_mfma_f32_16x16x32_bf16(a.hi, pre.bl[ks], acc, 0, 0, 0);
    acc = __builtin_amdgcn_mfma_f32_16x16x32_bf16(a.lo, pre.bh[ks], acc, 0, 0, 0);
  }

  float* dst = cb + w * 1088;            // [w][16][17] partials
#pragma unroll
  for (int r = 0; r < 4; r++) dst[(q * 4 + r) * 17 + mi] = acc[r];
  __syncthreads();
  if (epi){
    float v = 0.f;
#pragma unroll
    for (int w2 = 0; w2 < 8; w2++) v += cb[w2 * 1088 + er * 17 + ec];
    const float mult = multx ? multv : unpackf(mpack);
    ast(O + gi, packf(2.f * sigm(v) * mult));
  }
}

// ---- gates + fused LSTM cell ----
__device__ __forceinline__ void gates_phase(
    GatesPre gp, const u32* X, const u32* H,
    const u16* WihThi, const u16* WihTlo,
    const u16* WhhThi, const u16* WhhTlo,
    const float* bsum, float& creg, u32* O,
    int rm, int cn, int tid, float* cb, float* red)
{
  const int w = tid >> 6, lane = tid & 63;
  const int mi = lane & 15, q = lane >> 4;
  const int src = w >> 2;
  const u32* Ap = src ? H : X;
  const u16* Bh = src ? WhhThi : WihThi;
  const u16* Bl = src ? WhhTlo : WihTlo;
  const int kb = (w & 3) * 256 + q * 8;

  const u16* bh_p[4]; const u16* bl_p[4];
#pragma unroll
  for (int nt = 0; nt < 4; nt++){
    const size_t brow = (size_t)(nt * HD + cn + mi) * HD + kb;
    bh_p[nt] = Bh + brow; bl_p[nt] = Bl + brow;
  }
  // ks=2 B frags: issue BEFORE the A batch so their latency is absorbed by the
  // batch's single vmcnt(0) (they were previously serialized after it)
  v8s b2h[4], b2l[4];
#pragma unroll
  for (int nt = 0; nt < 4; nt++){
    b2h[nt] = *(const v8s*)(bh_p[nt] + 64);
    b2l[nt] = *(const v8s*)(bl_p[nt] + 64);
  }
  // A: batched coherent load, single waitcnt (covers b2h/b2l too)
  v4u ar[16];
  ald_batch16(Ap + (size_t)(rm + mi) * HD + kb, ar);

  v4f acc[4];
#pragma unroll
  for (int nt = 0; nt < 4; nt++) acc[nt] = (v4f){0.f, 0.f, 0.f, 0.f};
  // ks = 0,1 from pre-barrier prefetch
#pragma unroll
  for (int ks = 0; ks < 2; ks++){
    FragPair a = splitpair(ar[2 * ks], ar[2 * ks + 1]);
#pragma unroll
    for (int nt = 0; nt < 4; nt++){
      acc[nt] = __builtin_amdgcn_mfma_f32_16x16x32_bf16(a.hi, gp.bh[nt][ks], acc[nt], 0, 0, 0);
      acc[nt] = __builtin_amdgcn_mfma_f32_16x16x32_bf16(a.hi, gp.bl[nt][ks], acc[nt], 0, 0, 0);
      acc[nt] = __builtin_amdgcn_mfma_f32_16x16x32_bf16(a.lo, gp.bh[nt][ks], acc[nt], 0, 0, 0);
    }
  }
  // ks = 2 from registers loaded before the A batch
  {
    FragPair a = splitpair(ar[4], ar[5]);
#pragma unroll
    for (int nt = 0; nt < 4; nt++){
      acc[nt] = __builtin_amdgcn_mfma_f32_16x16x32_bf16(a.hi, b2h[nt], acc[nt], 0, 0, 0);
      acc[nt] = __builtin_amdgcn_mfma_f32_16x16x32_bf16(a.hi, b2l[nt], acc[nt], 0, 0, 0);
      acc[nt] = __builtin_amdgcn_mfma_f32_16x16x32_bf16(a.lo, b2h[nt], acc[nt], 0, 0, 0);
    }
  }
#pragma unroll
  for (int ks = 3; ks < 8; ks++){
    const int k = ks * 32;
    FragPair a = splitpair(ar[2 * ks], ar[2 * ks + 1]);
#pragma unroll
    for (int nt = 0; nt < 4; nt++){
      v8s bh = *(const v8s*)(bh_p[nt] + k);
      v8s bl = *(const v8s*)(bl_p[nt] + k);
      acc[nt] = __builtin_amdgcn_mfma_f32_16x16x32_bf16(a.hi, bh, acc[nt], 0, 0, 0);
      acc[nt] = __builtin_amdgcn_mfma_f32_16x16x32_bf16(a.hi, bl, acc[nt], 0, 0, 0);
      acc[nt] = __builtin_amdgcn_mfma_f32_16x16x32_bf16(a.lo, bh, acc[nt], 0, 0, 0);
    }
  }
#pragma unroll
  for (int nt = 0; nt < 4; nt++)
#pragma unroll
    for (int r = 0; r < 4; r++)
      cb[(w * 4 + nt) * 272 + (q * 4 + r) * 17 + mi] = acc[nt][r];
  __syncthreads();
  for (int e = tid; e < 1024; e += NTHR){
    const int qq = e >> 8, rc = e & 255, r = rc >> 4, c = rc & 15;
    float v = 0.f;
#pragma unroll
    for (int w2 = 0; w2 < 8; w2++) v += cb[(w2 * 4 + qq) * 272 + r * 17 + c];
    red[qq * 272 + r * 17 + c] = v;
  }
  __syncthreads();
  if (tid < 256){
    const int r = tid >> 4, c = tid & 15;
    const float g0 = red[0 * 272 + r * 17 + c] + bsum[0];
    const float g1 = red[1 * 272 + r * 17 + c] + bsum[1];
    const float g2 = red[2 * 272 + r * 17 + c] + bsum[2];
    const float g3 = red[3 * 272 + r * 17 + c] + bsum[3];
    const float ig = sigm(g0), fg = sigm(g1), cg = tanhf(g2), og = sigm(g3);
    const float cnew = fg * creg + ig * cg;
    creg = cnew;
    const float h = og * tanhf(cnew);
    ast(O + (rm + r) * HD + (cn + c), packf(h));
  }
}

extern "C" __global__ void __launch_bounds__(NTHR, 2)
moglstm_kernel(const float* __restrict__ x, const float* __restrict__ Wih,
               const float* __restrict__ Whh, const float* __restrict__ bih,
               const float* __restrict__ bhh, const float* __restrict__ Q,
               const float* __restrict__ Rw, const float* __restrict__ h0,
               const float* __restrict__ c0, float* __restrict__ out,
               uint8_t* __restrict__ ws)
{
  __shared__ float cb[32 * 272];
  __shared__ float red[4 * 272];
  __shared__ u16 shh[32 * 33], shl[32 * 33];

  // ---- carve workspace ----
  uint8_t* p = ws;
  u32* xA   = (u32*)p;     p += (size_t)BATCH * HD * 4;
  u32* xB   = (u32*)p;     p += (size_t)BATCH * HD * 4;
  u32* hA   = (u32*)p;     p += (size_t)BATCH * HD * 4;
  u32* hB   = (u32*)p;     p += (size_t)BATCH * HD * 4;
  u16* QThi  = (u16*)p;    p += (size_t)HD * HD * 2;
  u16* QTlo  = (u16*)p;    p += (size_t)HD * HD * 2;
  u16* RThi  = (u16*)p;    p += (size_t)HD * HD * 2;
  u16* RTlo  = (u16*)p;    p += (size_t)HD * HD * 2;
  u16* WihThi = (u16*)p;   p += (size_t)4 * HD * HD * 2;
  u16* WihTlo = (u16*)p;   p += (size_t)4 * HD * HD * 2;
  u16* WhhThi = (u16*)p;   p += (size_t)4 * HD * HD * 2;
  u16* WhhTlo = (u16*)p;   p += (size_t)4 * HD * HD * 2;
  int* flagsP = (int*)p;                           // [256*32] prep barrier, line-spread
  int* gfbase = flagsP + 256 * FLAG_STRIDE;        // 4 groups x (64*32) line-spread flags

  const int bid = blockIdx.x, tid = threadIdx.x;
  const int group = bid >> 6, member = bid & 63;
  const int rm = group * 16, cn = member * 16;
  int* gf = gfbase + group * (64 * FLAG_STRIDE);

  // ---- prep: split weights into hi/lo bf16 + transpose to WT[n][k]; init h ----
  for (int tile = bid; tile < 10240; tile += NBLK){
    const float* W; u16 *Th, *Tl; int N, kt, nt;
    if (tile < 1024)      { W = Q;   Th = QThi;   Tl = QTlo;   N = HD;     int tl = tile;        kt = tl >> 5; nt = tl & 31; }
    else if (tile < 2048) { W = Rw;  Th = RThi;   Tl = RTlo;   N = HD;     int tl = tile - 1024; kt = tl >> 5; nt = tl & 31; }
    else if (tile < 6144) { W = Wih; Th = WihThi; Tl = WihTlo; N = 4 * HD; int tl = tile - 2048; kt = tl >> 7; nt = tl & 127; }
    else                  { W = Whh; Th = WhhThi; Tl = WhhTlo; N = 4 * HD; int tl = tile - 6144; kt = tl >> 7; nt = tl & 127; }
    for (int e = tid; e < 1024; e += NTHR){
      const int ki = e >> 5, nj = e & 31;
      const float v = W[(size_t)(kt * 32 + ki) * N + nt * 32 + nj];
      const u16 hi = f2bf(v);
      shh[ki * 33 + nj] = hi;
      shl[ki * 33 + nj] = f2bf(v - bf2f(hi));
    }
    __syncthreads();
    for (int e = tid; e < 1024; e += NTHR){
      const int ni = e >> 5, kj = e & 31;
      Th[(size_t)(nt * 32 + ni) * HD + kt * 32 + kj] = shh[kj * 33 + ni];
      Tl[(size_t)(nt * 32 + ni) * HD + kt * 32 + kj] = shl[kj * 33 + ni];
    }
    __syncthreads();
  }
  for (int i = bid * NTHR + tid; i < BATCH * HD; i += NBLK * NTHR)
    hA[i] = packf(h0[i]);

  // hoist cell state + bias sums into registers (block<->tile mapping fixed)
  float creg = 0.f;
  float bsum[4] = {0.f, 0.f, 0.f, 0.f};
  if (tid < 256){
    const int r = tid >> 4, c = tid & 15, col = cn + c;
    creg = c0[(rm + r) * HD + col];
#pragma unroll
    for (int qq = 0; qq < 4; qq++) bsum[qq] = bih[qq * HD + col] + bhh[qq * HD + col];
  }

  // one-time heavyweight release for prep's plain stores, then full-grid barrier
  __threadfence();
  gbar_all(flagsP, 1, bid, tid);

  // ---- recurrence: 4 independent row groups, 64-block barriers ----
  u32 *hc = hA, *ho = hB;
  int bar = 0;
  MogPre pre = mog_pre(QThi, QTlo, cn, tid);
  for (int t = 0; t < SEQ; t++){
    // i=1: xt1 = 2s(ht0@Q)*x[:,t,:]
    mog_phase(pre, hc, x + (size_t)t * HD, nullptr, xA, rm, cn, tid, cb);
    pre = mog_pre(RThi, RTlo, cn, tid);
    bar++; gbar64(gf, bar, member, tid);
    // i=2: ht1 = 2s(xt1@R)*ht0
    mog_phase(pre, xA, nullptr, hc, ho, rm, cn, tid, cb);
    pre = mog_pre(QThi, QTlo, cn, tid);
    bar++; gbar64(gf, bar, member, tid);
    // i=3: xt2 = 2s(ht1@Q)*xt1
    mog_phase(pre, ho, nullptr, xA, xB, rm, cn, tid, cb);
    pre = mog_pre(RThi, RTlo, cn, tid);
    bar++; gbar64(gf, bar, member, tid);
    // i=4: ht2 = 2s(xt2@R)*ht1
    mog_phase(pre, xB, nullptr, ho, hc, rm, cn, tid, cb);
    pre = mog_pre(QThi, QTlo, cn, tid);
    bar++; gbar64(gf, bar, member, tid);
    // i=5: xt3 = 2s(ht2@Q)*xt2
    mog_phase(pre, hc, nullptr, xB, xA, rm, cn, tid, cb);
    GatesPre gp = gates_pre(WihThi, WihTlo, WhhThi, WhhTlo, cn, tid);
    bar++; gbar64(gf, bar, member, tid);
    // gates + cell: h_new -> other h buffer
    gates_phase(gp, xA, hc, WihThi, WihTlo, WhhThi, WhhTlo, bsum, creg, ho,
                rm, cn, tid, cb, red);
    pre = mog_pre(QThi, QTlo, cn, tid);
    bar++; gbar64(gf, bar, member, tid);
    u32* tswp = hc; hc = ho; ho = tswp;
  }

  // ---- output: each block writes its own 16x16 tile of h_final ----
  if (tid < 256){
    const int er = tid >> 4, ec = tid & 15;
    const int gi = (rm + er) * HD + (cn + ec);
    out[gi] = unpackf(ald(hc + gi));
  }
}

extern "C" void kernel_launch(void* const* d_in, const int* in_sizes, int n_in,
                              void* d_out, int out_size, void* d_ws, size_t ws_size,
                              hipStream_t stream)
{
  const float* x   = (const float*)d_in[0];
  const float* Wih = (const float*)d_in[1];
  const float* Whh = (const float*)d_in[2];
  const float* bih = (const float*)d_in[3];
  const float* bhh = (const float*)d_in[4];
  const float* Q   = (const float*)d_in[5];
  const float* Rw  = (const float*)d_in[6];
  const float* h0  = (const float*)d_in[7];
  const float* c0  = (const float*)d_in[8];
  float* out = (float*)d_out;
  uint8_t* ws = (uint8_t*)d_ws;
  void* args[] = { &x, &Wih, &Whh, &bih, &bhh, &Q, &Rw, &h0, &c0, &out, &ws };
  hipLaunchCooperativeKernel((void*)moglstm_kernel, dim3(NBLK), dim3(NTHR),
                             args, 0, stream);
}

// Round 2
// 21338.335 us; speedup vs baseline: 1.5110x; 1.0075x over previous
//
#include <hip/hip_runtime.h>
#include <stdint.h>

#define NBLK 256
#define NTHR 512          // 8 waves: K-split within block
#define BATCH 64
#define HD 1024
#define SEQ 512

// barrier flags: one per 128-B line to avoid MALL slice hotspots
#define FLAG_STRIDE 32

typedef unsigned short u16;
typedef uint32_t u32;
typedef __attribute__((ext_vector_type(8))) short v8s;        // 8 bf16 (MFMA A/B frag)
typedef __attribute__((ext_vector_type(4))) float v4f;        // MFMA C/D frag
typedef __attribute__((ext_vector_type(4))) unsigned int v4u; // dwordx4

__device__ __forceinline__ float bf2f(u16 u){
  union { float f; u32 i; } c; c.i = ((u32)u) << 16; return c.f;
}
__device__ __forceinline__ u16 f2bf(float f){  // round-to-nearest-even
  union { float f; u32 i; } c; c.f = f;
  u32 i = c.i;
  return (u16)((i + 0x7fffu + ((i >> 16) & 1u)) >> 16);
}
__device__ __forceinline__ float sigm(float v){ return 1.f / (1.f + __expf(-v)); }

// packed activation element: low16 = hi bf16, high16 = lo bf16; value = hi + lo
__device__ __forceinline__ u32 packf(float v){
  const u16 hi = f2bf(v);
  const u16 lo = f2bf(v - bf2f(hi));
  return (u32)hi | ((u32)lo << 16);
}
__device__ __forceinline__ float unpackf(u32 w){
  return bf2f((u16)(w & 0xffffu)) + bf2f((u16)(w >> 16));
}

// coherent (cache-bypassing) scalar access
__device__ __forceinline__ u32 ald(const u32* p){
  return __hip_atomic_load(p, __ATOMIC_RELAXED, __HIP_MEMORY_SCOPE_AGENT);
}
__device__ __forceinline__ void ast(u32* p, u32 v){
  __hip_atomic_store(p, v, __ATOMIC_RELAXED, __HIP_MEMORY_SCOPE_AGENT);
}
__device__ __forceinline__ int aldi(const int* p){
  return __hip_atomic_load(p, __ATOMIC_RELAXED, __HIP_MEMORY_SCOPE_AGENT);
}

// ---- batched coherent vector loads: N dwordx4, one waitcnt ----
// offsets: ks*128 + {0,16} bytes (lane's 8 consecutive u32 per 32-element k-step)
__device__ __forceinline__ void ald_batch8(const u32* p, v4u r[8]){
  asm volatile(
    "global_load_dwordx4 %0, %8, off sc0 sc1\n\t"
    "global_load_dwordx4 %1, %8, off offset:16 sc0 sc1\n\t"
    "global_load_dwordx4 %2, %8, off offset:128 sc0 sc1\n\t"
    "global_load_dwordx4 %3, %8, off offset:144 sc0 sc1\n\t"
    "global_load_dwordx4 %4, %8, off offset:256 sc0 sc1\n\t"
    "global_load_dwordx4 %5, %8, off offset:272 sc0 sc1\n\t"
    "global_load_dwordx4 %6, %8, off offset:384 sc0 sc1\n\t"
    "global_load_dwordx4 %7, %8, off offset:400 sc0 sc1\n\t"
    "s_waitcnt vmcnt(0)"
    : "=&v"(r[0]), "=&v"(r[1]), "=&v"(r[2]), "=&v"(r[3]),
      "=&v"(r[4]), "=&v"(r[5]), "=&v"(r[6]), "=&v"(r[7])
    : "v"(p) : "memory");
}
__device__ __forceinline__ void ald_batch16(const u32* p, v4u r[16]){
  asm volatile(
    "global_load_dwordx4 %0, %16, off sc0 sc1\n\t"
    "global_load_dwordx4 %1, %16, off offset:16 sc0 sc1\n\t"
    "global_load_dwordx4 %2, %16, off offset:128 sc0 sc1\n\t"
    "global_load_dwordx4 %3, %16, off offset:144 sc0 sc1\n\t"
    "global_load_dwordx4 %4, %16, off offset:256 sc0 sc1\n\t"
    "global_load_dwordx4 %5, %16, off offset:272 sc0 sc1\n\t"
    "global_load_dwordx4 %6, %16, off offset:384 sc0 sc1\n\t"
    "global_load_dwordx4 %7, %16, off offset:400 sc0 sc1\n\t"
    "global_load_dwordx4 %8, %16, off offset:512 sc0 sc1\n\t"
    "global_load_dwordx4 %9, %16, off offset:528 sc0 sc1\n\t"
    "global_load_dwordx4 %10, %16, off offset:640 sc0 sc1\n\t"
    "global_load_dwordx4 %11, %16, off offset:656 sc0 sc1\n\t"
    "global_load_dwordx4 %12, %16, off offset:768 sc0 sc1\n\t"
    "global_load_dwordx4 %13, %16, off offset:784 sc0 sc1\n\t"
    "global_load_dwordx4 %14, %16, off offset:896 sc0 sc1\n\t"
    "global_load_dwordx4 %15, %16, off offset:912 sc0 sc1\n\t"
    "s_waitcnt vmcnt(0)"
    : "=&v"(r[0]), "=&v"(r[1]), "=&v"(r[2]), "=&v"(r[3]),
      "=&v"(r[4]), "=&v"(r[5]), "=&v"(r[6]), "=&v"(r[7]),
      "=&v"(r[8]), "=&v"(r[9]), "=&v"(r[10]), "=&v"(r[11]),
      "=&v"(r[12]), "=&v"(r[13]), "=&v"(r[14]), "=&v"(r[15])
    : "v"(p) : "memory");
}

struct FragPair { v8s hi; v8s lo; };
// two dwordx4 of packed u32 -> (8 hi bf16, 8 lo bf16)
__device__ __forceinline__ FragPair splitpair(v4u w0, v4u w1){
  union { v8s v; u32 u[4]; } H, L;
#pragma unroll
  for (int i = 0; i < 2; i++){
    H.u[i]     = (w0[2*i] & 0xffffu) | (w0[2*i+1] << 16);
    L.u[i]     = (w0[2*i] >> 16)     | (w0[2*i+1] & 0xffff0000u);
    H.u[2 + i] = (w1[2*i] & 0xffffu) | (w1[2*i+1] << 16);
    L.u[2 + i] = (w1[2*i] >> 16)     | (w1[2*i+1] & 0xffff0000u);
  }
  FragPair f; f.hi = H.v; f.lo = L.v; return f;
}

// ---- full-grid barrier (prep only); flags spread one per 128-B line ----
__device__ __forceinline__ void gbar_all(int* flags, int target, int bid, int tid){
  __syncthreads();
  if (tid == 0)
    __hip_atomic_store(&flags[bid * FLAG_STRIDE], target, __ATOMIC_RELAXED, __HIP_MEMORY_SCOPE_AGENT);
  if (tid < 64){
    const int* p = flags + (tid * 4) * FLAG_STRIDE;
    for (;;){
      int a = aldi(p + 0 * FLAG_STRIDE), b = aldi(p + 1 * FLAG_STRIDE);
      int c = aldi(p + 2 * FLAG_STRIDE), d = aldi(p + 3 * FLAG_STRIDE);
      if (a >= target && b >= target && c >= target && d >= target) break;
      __builtin_amdgcn_s_sleep(1);
    }
  }
  __syncthreads();
}

// ---- pre-wait weight prefetch (independent of cross-block data) ----
// mog: ALL 4 k-steps prefetched -> zero post-wait weight loads in mog_phase
struct MogPre { v8s bh[4]; v8s bl[4]; };
__device__ __forceinline__ MogPre mog_pre(const u16* WThi, const u16* WTlo, int cn, int tid){
  const int w = tid >> 6, lane = tid & 63;
  const int mi = lane & 15, q = lane >> 4;
  const int kb = w * 128 + q * 8;
  const u16* bh_p = WThi + (size_t)(cn + mi) * HD + kb;
  const u16* bl_p = WTlo + (size_t)(cn + mi) * HD + kb;
  MogPre pre;
#pragma unroll
  for (int ks = 0; ks < 4; ks++){
    pre.bh[ks] = *(const v8s*)(bh_p + ks * 32);
    pre.bl[ks] = *(const v8s*)(bl_p + ks * 32);
  }
  return pre;
}
// gates: ks=0,1 prefetched pre-wait (16 v8s = 64 VGPR live across wait)
struct GatesPre { v8s bh[4][2]; v8s bl[4][2]; };
__device__ __forceinline__ GatesPre gates_pre(
    const u16* WihThi, const u16* WihTlo,
    const u16* WhhThi, const u16* WhhTlo, int cn, int tid){
  const int w = tid >> 6, lane = tid & 63;
  const int mi = lane & 15, q = lane >> 4;
  const int src = w >> 2;
  const u16* Bh = src ? WhhThi : WihThi;
  const u16* Bl = src ? WhhTlo : WihTlo;
  const int kb = (w & 3) * 256 + q * 8;
  GatesPre g;
#pragma unroll
  for (int nt = 0; nt < 4; nt++){
    const size_t brow = (size_t)(nt * HD + cn + mi) * HD + kb;
#pragma unroll
    for (int ks = 0; ks < 2; ks++){
      g.bh[nt][ks] = *(const v8s*)(Bh + brow + ks * 32);
      g.bl[nt][ks] = *(const v8s*)(Bl + brow + ks * 32);
    }
  }
  return g;
}

// ---- one mogrify matmul phase: O = 2*sigmoid(A @ W) * mult ----
// Fine-grained sync: each wave waits ONLY on the 8 producers of its k-slice
// (members 8w..8w+7 at flag >= donebar-1), then loads+computes immediately.
// Producer flag (donebar) is stored after the epilogue-drain syncthreads.
// WAR safety: every epilogue follows the in-block join of 8 waves whose
// producer-wait union = all 64 members of the previous phase, so by induction
// all members have finished all earlier phases before any buffer is overwritten.
__device__ __forceinline__ void mog_phase(
    MogPre pre, const u32* A, int donebar,
    const float* multx, const u32* M, u32* O,
    int rm, int cn, int tid, float* cb, int* gf, int member)
{
  const int w = tid >> 6, lane = tid & 63;
  const int mi = lane & 15, q = lane >> 4;
  const int kb = w * 128 + q * 8;
  // epilogue multiplier: issue ASAP (own tile, produced >=2 phases ago by own block)
  const int er = tid >> 4, ec = tid & 15;
  const int gi = (rm + er) * HD + (cn + ec);
  const bool epi = (tid < 256);
  float multv = 0.f; u32 mpack = 0;
  if (epi){
    if (multx) multv = __builtin_nontemporal_load(multx + (size_t)(rm + er) * (SEQ * HD) + (cn + ec));
    else       mpack = ald(M + gi);
  }
  // per-wave producer wait (8 flags, one line each)
  {
    const int abar = donebar - 1;
    const int* fp = gf + (8 * w + (lane & 7)) * FLAG_STRIDE;
    while (aldi(fp) < abar) __builtin_amdgcn_s_sleep(1);
  }
  // A: one batched coherent load (single MALL round trip); all B frags already in regs
  v4u ar[8];
  ald_batch8(A + (size_t)(rm + mi) * HD + kb, ar);

  v4f acc = {0.f, 0.f, 0.f, 0.f};
#pragma unroll
  for (int ks = 0; ks < 4; ks++){
    FragPair a = splitpair(ar[2 * ks], ar[2 * ks + 1]);
    acc = __builtin_amdgcn_mfma_f32_16x16x32_bf16(a.hi, pre.bh[ks], acc, 0, 0, 0);
    acc = __builtin_amdgcn_mfma_f32_16x16x32_bf16(a.hi, pre.bl[ks], acc, 0, 0, 0);
    acc = __builtin_amdgcn_mfma_f32_16x16x32_bf16(a.lo, pre.bh[ks], acc, 0, 0, 0);
  }

  float* dst = cb + w * 1088;            // [w][16][17] partials
#pragma unroll
  for (int r = 0; r < 4; r++) dst[(q * 4 + r) * 17 + mi] = acc[r];
  __syncthreads();
  if (epi){
    float v = 0.f;
#pragma unroll
    for (int w2 = 0; w2 < 8; w2++) v += cb[w2 * 1088 + er * 17 + ec];
    const float mult = multx ? multv : unpackf(mpack);
    ast(O + gi, packf(2.f * sigm(v) * mult));
  }
  __syncthreads();   // drains epilogue ast stores (vmcnt0) before flag store
  if (tid == 0)
    __hip_atomic_store(&gf[member * FLAG_STRIDE], donebar, __ATOMIC_RELAXED, __HIP_MEMORY_SCOPE_AGENT);
}

// ---- gates + fused LSTM cell ----
// Waves 0-3 (X consumers) wait on 16 producers of their xA k-slice.
// Waves 4-7 (H consumers) need no wait: hc was produced 2 phases earlier and
// the in-block completion of i=5 already implies all-64 completion of i=4.
__device__ __forceinline__ void gates_phase(
    GatesPre gp, const u32* X, const u32* H, int donebar,
    const u16* WihThi, const u16* WihTlo,
    const u16* WhhThi, const u16* WhhTlo,
    const float* bsum, float& creg, u32* O,
    int rm, int cn, int tid, float* cb, float* red, int* gf, int member)
{
  const int w = tid >> 6, lane = tid & 63;
  const int mi = lane & 15, q = lane >> 4;
  const int src = w >> 2;
  const u32* Ap = src ? H : X;
  const u16* Bh = src ? WhhThi : WihThi;
  const u16* Bl = src ? WhhTlo : WihTlo;
  const int kb = (w & 3) * 256 + q * 8;

  const u16* bh_p[4]; const u16* bl_p[4];
#pragma unroll
  for (int nt = 0; nt < 4; nt++){
    const size_t brow = (size_t)(nt * HD + cn + mi) * HD + kb;
    bh_p[nt] = Bh + brow; bl_p[nt] = Bl + brow;
  }
  // ks=2 B frags: issue BEFORE the wait+A batch so their latency is absorbed
  v8s b2h[4], b2l[4];
#pragma unroll
  for (int nt = 0; nt < 4; nt++){
    b2h[nt] = *(const v8s*)(bh_p[nt] + 64);
    b2l[nt] = *(const v8s*)(bl_p[nt] + 64);
  }
  // per-wave producer wait: X k-slice (w&3)*256 -> members (w&3)*16 .. +15
  if (!src){
    const int abar = donebar - 1;
    const int* fp = gf + ((w & 3) * 16 + (lane & 15)) * FLAG_STRIDE;
    while (aldi(fp) < abar) __builtin_amdgcn_s_sleep(1);
  }
  // A: batched coherent load, single waitcnt (covers b2h/b2l too)
  v4u ar[16];
  ald_batch16(Ap + (size_t)(rm + mi) * HD + kb, ar);

  v4f acc[4];
#pragma unroll
  for (int nt = 0; nt < 4; nt++) acc[nt] = (v4f){0.f, 0.f, 0.f, 0.f};
  // ks = 0,1 from pre-wait prefetch
#pragma unroll
  for (int ks = 0; ks < 2; ks++){
    FragPair a = splitpair(ar[2 * ks], ar[2 * ks + 1]);
#pragma unroll
    for (int nt = 0; nt < 4; nt++){
      acc[nt] = __builtin_amdgcn_mfma_f32_16x16x32_bf16(a.hi, gp.bh[nt][ks], acc[nt], 0, 0, 0);
      acc[nt] = __builtin_amdgcn_mfma_f32_16x16x32_bf16(a.hi, gp.bl[nt][ks], acc[nt], 0, 0, 0);
      acc[nt] = __builtin_amdgcn_mfma_f32_16x16x32_bf16(a.lo, gp.bh[nt][ks], acc[nt], 0, 0, 0);
    }
  }
  // ks = 2 from registers loaded before the A batch
  {
    FragPair a = splitpair(ar[4], ar[5]);
#pragma unroll
    for (int nt = 0; nt < 4; nt++){
      acc[nt] = __builtin_amdgcn_mfma_f32_16x16x32_bf16(a.hi, b2h[nt], acc[nt], 0, 0, 0);
      acc[nt] = __builtin_amdgcn_mfma_f32_16x16x32_bf16(a.hi, b2l[nt], acc[nt], 0, 0, 0);
      acc[nt] = __builtin_amdgcn_mfma_f32_16x16x32_bf16(a.lo, b2h[nt], acc[nt], 0, 0, 0);
    }
  }
#pragma unroll
  for (int ks = 3; ks < 8; ks++){
    const int k = ks * 32;
    FragPair a = splitpair(ar[2 * ks], ar[2 * ks + 1]);
#pragma unroll
    for (int nt = 0; nt < 4; nt++){
      v8s bh = *(const v8s*)(bh_p[nt] + k);
      v8s bl = *(const v8s*)(bl_p[nt] + k);
      acc[nt] = __builtin_amdgcn_mfma_f32_16x16x32_bf16(a.hi, bh, acc[nt], 0, 0, 0);
      acc[nt] = __builtin_amdgcn_mfma_f32_16x16x32_bf16(a.hi, bl, acc[nt], 0, 0, 0);
      acc[nt] = __builtin_amdgcn_mfma_f32_16x16x32_bf16(a.lo, bh, acc[nt], 0, 0, 0);
    }
  }
#pragma unroll
  for (int nt = 0; nt < 4; nt++)
#pragma unroll
    for (int r = 0; r < 4; r++)
      cb[(w * 4 + nt) * 272 + (q * 4 + r) * 17 + mi] = acc[nt][r];
  __syncthreads();
  for (int e = tid; e < 1024; e += NTHR){
    const int qq = e >> 8, rc = e & 255, r = rc >> 4, c = rc & 15;
    float v = 0.f;
#pragma unroll
    for (int w2 = 0; w2 < 8; w2++) v += cb[(w2 * 4 + qq) * 272 + r * 17 + c];
    red[qq * 272 + r * 17 + c] = v;
  }
  __syncthreads();
  if (tid < 256){
    const int r = tid >> 4, c = tid & 15;
    const float g0 = red[0 * 272 + r * 17 + c] + bsum[0];
    const float g1 = red[1 * 272 + r * 17 + c] + bsum[1];
    const float g2 = red[2 * 272 + r * 17 + c] + bsum[2];
    const float g3 = red[3 * 272 + r * 17 + c] + bsum[3];
    const float ig = sigm(g0), fg = sigm(g1), cg = tanhf(g2), og = sigm(g3);
    const float cnew = fg * creg + ig * cg;
    creg = cnew;
    const float h = og * tanhf(cnew);
    ast(O + (rm + r) * HD + (cn + c), packf(h));
  }
  __syncthreads();   // drains epilogue ast stores before flag store
  if (tid == 0)
    __hip_atomic_store(&gf[member * FLAG_STRIDE], donebar, __ATOMIC_RELAXED, __HIP_MEMORY_SCOPE_AGENT);
}

extern "C" __global__ void __launch_bounds__(NTHR, 2)
moglstm_kernel(const float* __restrict__ x, const float* __restrict__ Wih,
               const float* __restrict__ Whh, const float* __restrict__ bih,
               const float* __restrict__ bhh, const float* __restrict__ Q,
               const float* __restrict__ Rw, const float* __restrict__ h0,
               const float* __restrict__ c0, float* __restrict__ out,
               uint8_t* __restrict__ ws)
{
  __shared__ float cb[32 * 272];
  __shared__ float red[4 * 272];
  __shared__ u16 shh[32 * 33], shl[32 * 33];

  // ---- carve workspace ----
  uint8_t* p = ws;
  u32* xA   = (u32*)p;     p += (size_t)BATCH * HD * 4;
  u32* xB   = (u32*)p;     p += (size_t)BATCH * HD * 4;
  u32* hA   = (u32*)p;     p += (size_t)BATCH * HD * 4;
  u32* hB   = (u32*)p;     p += (size_t)BATCH * HD * 4;
  u16* QThi  = (u16*)p;    p += (size_t)HD * HD * 2;
  u16* QTlo  = (u16*)p;    p += (size_t)HD * HD * 2;
  u16* RThi  = (u16*)p;    p += (size_t)HD * HD * 2;
  u16* RTlo  = (u16*)p;    p += (size_t)HD * HD * 2;
  u16* WihThi = (u16*)p;   p += (size_t)4 * HD * HD * 2;
  u16* WihTlo = (u16*)p;   p += (size_t)4 * HD * HD * 2;
  u16* WhhThi = (u16*)p;   p += (size_t)4 * HD * HD * 2;
  u16* WhhTlo = (u16*)p;   p += (size_t)4 * HD * HD * 2;
  int* flagsP = (int*)p;                           // [256*32] prep barrier, line-spread
  int* gfbase = flagsP + 256 * FLAG_STRIDE;        // 4 groups x (64*32) line-spread flags

  const int bid = blockIdx.x, tid = threadIdx.x;
  const int group = bid >> 6, member = bid & 63;
  const int rm = group * 16, cn = member * 16;
  int* gf = gfbase + group * (64 * FLAG_STRIDE);

  // ---- prep: split weights into hi/lo bf16 + transpose to WT[n][k]; init h ----
  for (int tile = bid; tile < 10240; tile += NBLK){
    const float* W; u16 *Th, *Tl; int N, kt, nt;
    if (tile < 1024)      { W = Q;   Th = QThi;   Tl = QTlo;   N = HD;     int tl = tile;        kt = tl >> 5; nt = tl & 31; }
    else if (tile < 2048) { W = Rw;  Th = RThi;   Tl = RTlo;   N = HD;     int tl = tile - 1024; kt = tl >> 5; nt = tl & 31; }
    else if (tile < 6144) { W = Wih; Th = WihThi; Tl = WihTlo; N = 4 * HD; int tl = tile - 2048; kt = tl >> 7; nt = tl & 127; }
    else                  { W = Whh; Th = WhhThi; Tl = WhhTlo; N = 4 * HD; int tl = tile - 6144; kt = tl >> 7; nt = tl & 127; }
    for (int e = tid; e < 1024; e += NTHR){
      const int ki = e >> 5, nj = e & 31;
      const float v = W[(size_t)(kt * 32 + ki) * N + nt * 32 + nj];
      const u16 hi = f2bf(v);
      shh[ki * 33 + nj] = hi;
      shl[ki * 33 + nj] = f2bf(v - bf2f(hi));
    }
    __syncthreads();
    for (int e = tid; e < 1024; e += NTHR){
      const int ni = e >> 5, kj = e & 31;
      Th[(size_t)(nt * 32 + ni) * HD + kt * 32 + kj] = shh[kj * 33 + ni];
      Tl[(size_t)(nt * 32 + ni) * HD + kt * 32 + kj] = shl[kj * 33 + ni];
    }
    __syncthreads();
  }
  for (int i = bid * NTHR + tid; i < BATCH * HD; i += NBLK * NTHR)
    hA[i] = packf(h0[i]);
  // zero the fine-grained flag region before anyone polls it
  for (int i = bid * NTHR + tid; i < 4 * 64 * FLAG_STRIDE; i += NBLK * NTHR)
    gfbase[i] = 0;

  // hoist cell state + bias sums into registers (block<->tile mapping fixed)
  float creg = 0.f;
  float bsum[4] = {0.f, 0.f, 0.f, 0.f};
  if (tid < 256){
    const int r = tid >> 4, c = tid & 15, col = cn + c;
    creg = c0[(rm + r) * HD + col];
#pragma unroll
    for (int qq = 0; qq < 4; qq++) bsum[qq] = bih[qq * HD + col] + bhh[qq * HD + col];
  }

  // one-time heavyweight release for prep's plain stores, then full-grid barrier
  __threadfence();
  gbar_all(flagsP, 1, bid, tid);

  // ---- recurrence: 4 independent row groups, fine-grained per-wave waits ----
  u32 *hc = hA, *ho = hB;
  int bar = 0;
  MogPre pre = mog_pre(QThi, QTlo, cn, tid);
  for (int t = 0; t < SEQ; t++){
    // i=1: xt1 = 2s(ht0@Q)*x[:,t,:]
    bar++;
    mog_phase(pre, hc, bar, x + (size_t)t * HD, nullptr, xA, rm, cn, tid, cb, gf, member);
    pre = mog_pre(RThi, RTlo, cn, tid);
    // i=2: ht1 = 2s(xt1@R)*ht0
    bar++;
    mog_phase(pre, xA, bar, nullptr, hc, ho, rm, cn, tid, cb, gf, member);
    pre = mog_pre(QThi, QTlo, cn, tid);
    // i=3: xt2 = 2s(ht1@Q)*xt1
    bar++;
    mog_phase(pre, ho, bar, nullptr, xA, xB, rm, cn, tid, cb, gf, member);
    pre = mog_pre(RThi, RTlo, cn, tid);
    // i=4: ht2 = 2s(xt2@R)*ht1
    bar++;
    mog_phase(pre, xB, bar, nullptr, ho, hc, rm, cn, tid, cb, gf, member);
    pre = mog_pre(QThi, QTlo, cn, tid);
    // i=5: xt3 = 2s(ht2@Q)*xt2
    bar++;
    mog_phase(pre, hc, bar, nullptr, xB, xA, rm, cn, tid, cb, gf, member);
    GatesPre gp = gates_pre(WihThi, WihTlo, WhhThi, WhhTlo, cn, tid);
    // gates + cell: h_new -> other h buffer
    bar++;
    gates_phase(gp, xA, hc, bar, WihThi, WihTlo, WhhThi, WhhTlo, bsum, creg, ho,
                rm, cn, tid, cb, red, gf, member);
    pre = mog_pre(QThi, QTlo, cn, tid);
    u32* tswp = hc; hc = ho; ho = tswp;
  }

  // ---- output: each block writes its own 16x16 tile of h_final ----
  if (tid < 256){
    const int er = tid >> 4, ec = tid & 15;
    const int gi = (rm + er) * HD + (cn + ec);
    out[gi] = unpackf(ald(hc + gi));
  }
}

extern "C" void kernel_launch(void* const* d_in, const int* in_sizes, int n_in,
                              void* d_out, int out_size, void* d_ws, size_t ws_size,
                              hipStream_t stream)
{
  const float* x   = (const float*)d_in[0];
  const float* Wih = (const float*)d_in[1];
  const float* Whh = (const float*)d_in[2];
  const float* bih = (const float*)d_in[3];
  const float* bhh = (const float*)d_in[4];
  const float* Q   = (const float*)d_in[5];
  const float* Rw  = (const float*)d_in[6];
  const float* h0  = (const float*)d_in[7];
  const float* c0  = (const float*)d_in[8];
  float* out = (float*)d_out;
  uint8_t* ws = (uint8_t*)d_ws;
  void* args[] = { &x, &Wih, &Whh, &bih, &bhh, &Q, &Rw, &h0, &c0, &out, &ws };
  hipLaunchCooperativeKernel((void*)moglstm_kernel, dim3(NBLK), dim3(NTHR),
                             args, 0, stream);
}